// Round 1
// 659.808 us; speedup vs baseline: 1.1215x; 1.1215x over previous
//
#include <hip/hip_runtime.h>

// Murray single-area 2-unit RNN scan — lane-pair-split version.
//
// B=8192 independent sequential chains of T*spb=8000 sub-steps -> the kernel is
// bound by per-wave serial instruction issue (1 wave/SIMD cannot exceed
// ~1 VALU instr / 4 cy; trans ops ~quarter rate). Previous version: one thread
// per chain, both units in-thread = 18 VALU + 4 trans per sub-step ~= 145
// cy/sub-step (measured). This version splits the two units of a chain across
// a LANE PAIR (lane 2c = unit0, lane 2c+1 = unit1); the cross-unit coupling
// s_other is exchanged with one full-rate DPP quad_perm swap per sub-step.
// Per-wave serial cost drops to 10 VALU + 2 trans per sub-step (~72 cy).
//
// Numerics identical to the previous (verified) kernel:
//   x = -C*log2e * act;  rate = INVC * (x * rcp(1-exp2(x))),  INVC = -ln2/C
//   window guard |x| < 1e-5 -> scaled rate = -log2e (limit 1/C), NOT exact==0:
//   hw exp2 can round to 1.0 for tiny x -> d=0 -> rcp=inf -> NaN cascade.

#define AF    270.0f
#define BF    108.0f
#define CF    0.154f
#define DTF   0.001f
#define I0F   0.334f
#define TAUF  0.06f
#define GAMF  0.641f
#define LOG2EF 1.44269504088896340736f
#define LN2F   0.69314718055994530942f

#if __has_builtin(__builtin_amdgcn_exp2f)
#define EXP2F(x) __builtin_amdgcn_exp2f(x)
#else
#define EXP2F(x) exp2f(x)
#endif

#if __has_builtin(__builtin_amdgcn_rcpf)
#define RCPF(x) __builtin_amdgcn_rcpf(x)
#else
#define RCPF(x) (1.0f / (x))
#endif

// Swap adjacent lanes (0<->1, 2<->3, ...): DPP quad_perm [1,0,3,2] = 0xB1.
__device__ __forceinline__ float dpp_swap1(float v) {
  return __int_as_float(
      __builtin_amdgcn_mov_dpp(__float_as_int(v), 0xB1, 0xF, 0xF, true));
}

struct Consts {
  float Xs, Xo;   // coeffs of s_self / s_other in x (A and -C*log2e folded in)
  float P, Q;     // x contribution of input: xq = P*in + Q
  float K1;       // 1 - sub_dt/TAU
  float K2C;      // sub_dt*GAMMA*INVC (applied to (1-s) * x/denom)
  float INVC;     // rate = INVC * r2 ; INVC = -ln2/C
};

// One sub-step for THIS lane's unit. r2 holds the (scaled) rate of this step.
__device__ __forceinline__ void substep(const Consts& c, float xq,
                                        float& s, float& r2) {
  float so = dpp_swap1(s);          // partner unit's state
  float p  = fmaf(c.Xs, s, xq);     // independent of the dpp -> overlaps it
  float x  = fmaf(c.Xo, so, p);
  float e  = EXP2F(x);
  float d  = 1.0f - e;
  float t  = x * RCPF(d);
  // near act==0: rate -> 1/C  <=>  scaled r2 -> -log2e (window, not ==0)
  r2 = (__builtin_fabsf(x) < 1e-5f) ? -LOG2EF : t;
  float u = fmaf(-s, r2, r2);       // (1-s)*r2
  s = fmaf(c.K2C, u, c.K1 * s);
}

// One bin: spb sub-steps; outputs rate of the LAST sub-step.
template <int SPB>
__device__ __forceinline__ void bin(const Consts& c, int spb, float in,
                                    float& s, float& rt) {
  float xq = fmaf(c.P, in, c.Q);
  float r2 = -LOG2EF;
  if (SPB > 0) {
#pragma unroll
    for (int k = 0; k < SPB; ++k) substep(c, xq, s, r2);
  } else {
    for (int k = 0; k < spb; ++k) substep(c, xq, s, r2);
  }
  rt = c.INVC * r2;
}

template <int SPB>
__device__ __forceinline__ void run_loop(const Consts& c, int spb, int T,
                                         const float* __restrict__ ip,
                                         float* __restrict__ sp,
                                         float* __restrict__ rp, float& s) {
  // Register prefetch ring, PF bins deep (statically indexed via full unroll).
  // One 4B load per bin; a 64B line covers 16 bins of this lane, so the HBM
  // miss (~900 cy) is amortized and hidden by the PF*SPB*~72cy lead.
  constexpr int PF = 8;
  const int Tm1 = T - 1;
  float buf[PF];
#pragma unroll
  for (int i = 0; i < PF; ++i) buf[i] = ip[2 * min(i, Tm1)];
  int t0 = 0;
  for (; t0 + PF <= T; t0 += PF) {
#pragma unroll
    for (int j = 0; j < PF; ++j) {
      // issue next-chunk load early (clamped; clamped values never consumed)
      float nxt = ip[2 * min(t0 + PF + j, Tm1)];
      float rt;
      bin<SPB>(c, spb, buf[j], s, rt);
      const int t = t0 + j;
      sp[2 * t] = s;
      rp[2 * t] = rt;
      buf[j] = nxt;
    }
  }
  for (; t0 < T; ++t0) {  // tail (T % PF)
    float rt;
    bin<SPB>(c, spb, ip[2 * t0], s, rt);
    sp[2 * t0] = s;
    rp[2 * t0] = rt;
  }
}

__global__ __launch_bounds__(64, 1)
void murray_kernel(const float* __restrict__ inp, const float* __restrict__ h0,
                   const float* __restrict__ Jm, const int* __restrict__ spb_p,
                   float* __restrict__ out, int B, int T) {
  const int tid = blockIdx.x * 64 + threadIdx.x;
  const int cB = tid >> 1;      // chain (batch element)
  const int u  = tid & 1;       // unit within the chain
  if (cB >= B) return;
  const int spb = *spb_p;

  // current_j = s0*J[0][j] + s1*J[1][j] + I0 + in_j ; J row-major in Jm.
  // unit u: self coeff J[u][u], other coeff J[1-u][u].
  const float Jself = u ? Jm[3] : Jm[0];
  const float Joth  = u ? Jm[1] : Jm[2];
  const float sub_dt = DTF / (float)spb;
  const float NC = -CF * LOG2EF;  // fold exp -> exp2

  Consts c;
  c.Xs = NC * AF * Jself;
  c.Xo = NC * AF * Joth;
  c.P  = NC * AF;
  c.Q  = NC * fmaf(AF, I0F, -BF);
  c.K1 = 1.0f - sub_dt / TAUF;
  c.INVC = -LN2F / CF;
  c.K2C = sub_dt * GAMF * c.INVC;

  float s = h0[2 * cB + u];

  const size_t row = (size_t)(2 * T);
  const float* ip = inp + (size_t)cB * row + u;
  float* sp = out + (size_t)cB * row + u;                       // states [B,T,2]
  float* rp = out + (size_t)B * row + (size_t)cB * row + u;     // rates  [B,T,2]
  float* fp = out + (size_t)B * row * 2 + (size_t)(2 * cB + u); // final  [1,B,2]

  if (spb == 4) {
    run_loop<4>(c, spb, T, ip, sp, rp, s);
  } else {
    run_loop<0>(c, spb, T, ip, sp, rp, s);
  }

  fp[0] = s;
}

extern "C" void kernel_launch(void* const* d_in, const int* in_sizes, int n_in,
                              void* d_out, int out_size, void* d_ws, size_t ws_size,
                              hipStream_t stream) {
  const float* inp = (const float*)d_in[0];
  const float* h0  = (const float*)d_in[1];
  const float* J   = (const float*)d_in[2];
  const int* spb   = (const int*)d_in[3];
  float* out = (float*)d_out;

  const int B = in_sizes[1] / 2;            // h0 is [1,B,2]
  const int T = in_sizes[0] / (2 * B);      // input is [B,T,2]
  const int threads = 2 * B;                // one lane per (chain, unit)
  const int blocks = (threads + 63) / 64;

  murray_kernel<<<blocks, 64, 0, stream>>>(inp, h0, J, spb, out, B, T);
}